// Round 10
// baseline (14166.504 us; speedup 1.0000x reference)
//
#include <hip/hip_runtime.h>

#define SEQ  4096
#define NB   64
#define NI   64
#define NH   256

typedef short  bf16x8 __attribute__((ext_vector_type(8)));
typedef short  bf16x4 __attribute__((ext_vector_type(4)));
typedef float  f32x4  __attribute__((ext_vector_type(4)));
typedef float  f32x2  __attribute__((ext_vector_type(2)));

#define SRZ (-1.4426950408889634f)   /* -log2(e):  exp(-x) = 2^(SRZ*x) */
#define SN  (-2.8853900817779268f)   /* -2log2(e): exp(-2y) = 2^(SN*y) */

__device__ __forceinline__ unsigned short f2bf(float f) {
    union { float f; unsigned u; } v; v.f = f;
    return (unsigned short)((v.u + 0x7fffu + ((v.u >> 16) & 1u)) >> 16);
}
__device__ __forceinline__ float bflo(int p) {
    union { int i; float f; } u; u.i = p << 16; return u.f;
}
__device__ __forceinline__ float bfhi(int p) {
    union { int i; float f; } u; u.i = p & 0xffff0000; return u.f;
}
__device__ __forceinline__ float fast_rcp(float x) { return __builtin_amdgcn_rcpf(x); }
__device__ __forceinline__ float ex2(float x) { return __builtin_amdgcn_exp2f(x); }
// packed bf16 convert (RNE) -- same rounding as f2bf, 1 inst for 2 values
__device__ __forceinline__ int cvtpk_bf16(float lo, float hi) {
    int r; asm("v_cvt_pk_bf16_f32 %0, %1, %2" : "=v"(r) : "v"(lo), "v"(hi));
    return r;
}
// two packed bf16 (lo16,hi16 of p) -> f32x2
__device__ __forceinline__ f32x2 bfup2(int p) {
    f32x2 r; r[0] = bflo(p); r[1] = bfhi(p); return r;
}
__device__ __forceinline__ f32x4 mfma16(bf16x8 a, bf16x8 b, f32x4 c) {
    return __builtin_amdgcn_mfma_f32_16x16x32_bf16(a, b, c, 0, 0, 0);
}
__device__ __forceinline__ bf16x8 ldfrag(const float* p) {
    float4 a = *(const float4*)p;
    float4 b = *(const float4*)(p + 4);
    bf16x8 r;
    r[0] = (short)f2bf(a.x); r[1] = (short)f2bf(a.y);
    r[2] = (short)f2bf(a.z); r[3] = (short)f2bf(a.w);
    r[4] = (short)f2bf(b.x); r[5] = (short)f2bf(b.y);
    r[6] = (short)f2bf(b.z); r[7] = (short)f2bf(b.w);
    return r;
}
// scaled variant: weights pre-scaled so loop transcendentals are bare v_exp
__device__ __forceinline__ bf16x8 ldfrag_s(const float* p, float s) {
    float4 a = *(const float4*)p;
    float4 b = *(const float4*)(p + 4);
    bf16x8 r;
    r[0] = (short)f2bf(a.x*s); r[1] = (short)f2bf(a.y*s);
    r[2] = (short)f2bf(a.z*s); r[3] = (short)f2bf(a.w*s);
    r[4] = (short)f2bf(b.x*s); r[5] = (short)f2bf(b.y*s);
    r[6] = (short)f2bf(b.z*s); r[7] = (short)f2bf(b.w*s);
    return r;
}

// ============ xg precompute + one-time wn67 bf16 scratch ====================
// Gate planes pre-scaled: r,z by -log2e; n by -2log2e (exp2 folding).
__global__ __launch_bounds__(1024) void xg_pre(
        const float* __restrict__ x, const float* __restrict__ w_ih,
        const float* __restrict__ w_hh,
        const float* __restrict__ b_ih, const float* __restrict__ b_hh,
        short* __restrict__ xg, short* __restrict__ wnsc,
        size_t plane, int t0, int ns)
{
    const int tid = threadIdx.x, wv = tid >> 6, lane = tid & 63;
    const int nn = lane & 15, q = lane >> 4;
    const int jb = wv;

    // one-time: (-2log2e)-scaled n-gate W_hh chunks 6-7 -> global scratch (32KB)
    if (t0 == 0 && blockIdx.x == 0) {
        bf16x8 f6 = ldfrag_s(w_hh + (2 * NH + wv * 16 + nn) * NH + 6 * 32 + q * 8, SN);
        bf16x8 f7 = ldfrag_s(w_hh + (2 * NH + wv * 16 + nn) * NH + 7 * 32 + q * 8, SN);
        *(bf16x8*)(wnsc + ((size_t)wv * 64 + lane) * 16)     = f6;
        *(bf16x8*)(wnsc + ((size_t)wv * 64 + lane) * 16 + 8) = f7;
    }

    bf16x8 w[3][2];
    float bias[3];
    const float sc[3] = { SRZ, SRZ, SN };
    #pragma unroll
    for (int g = 0; g < 3; ++g) {
        const int row = g * NH + jb * 16 + nn;
        w[g][0] = ldfrag(w_ih + row * NI + q * 8);
        w[g][1] = ldfrag(w_ih + row * NI + 32 + q * 8);
        bias[g] = b_ih[row] + (g < 2 ? b_hh[row] : 0.f);
    }

    const int NT = ns * 4;                       // 16-row tiles in chunk
    for (int rt = blockIdx.x; rt < NT; rt += gridDim.x) {
        const float* xr = x + ((size_t)t0 * NB + (size_t)rt * 16 + nn) * NI + q * 8;
        bf16x8 a0 = ldfrag(xr);
        bf16x8 a1 = ldfrag(xr + 32);
        #pragma unroll
        for (int g = 0; g < 3; ++g) {
            f32x4 acc = {0.f, 0.f, 0.f, 0.f};
            acc = mfma16(a0, w[g][0], acc);
            acc = mfma16(a1, w[g][1], acc);
            bf16x4 v;
            #pragma unroll
            for (int m = 0; m < 4; ++m)
                v[m] = (short)f2bf((acc[m] + bias[g]) * sc[g]);
            *(bf16x4*)(xg + (size_t)g * plane +
                       (((size_t)rt * 16 + jb) * 64 + lane) * 4) = v;
        }
    }
}

// ============ recurrent kernel ==============================================
// R9 ledger: step 2460cyc/SIMD = VALU 1345 + MFMA 1020 SERIAL SUM -- per-step
// barrier phase-aligns all waves, so the two pipes never overlap. Fixes:
//  1. GATE-SPLIT SCHEDULE: phase1 = ar+an chains (16 MFMA, one av read, FC
//     ride-along); phase2 = az chain (8 MFMA, av re-read) issued immediately
//     before the r-sigmoid/tanh trans block. az MFMAs are independent of the
//     r/tanh VALU work -> in-order wave issue interleaves them; the matrix
//     pipe runs under the trans chain (~340cyc hidden). z is only needed for
//     the final h blend, so only its sigmoid is an exposed tail. Per-gate
//     accumulation order c=0..7 unchanged (bit-identical MFMA math).
//     LDS +128KB/step (re-read) is safe: R7 proved bytes non-binding.
//  2. exp2 FOLDING: wr/wz/xg_rz pre-scaled by -log2e, wn/bhn/xg_n by -2log2e
//     -> all three __expf become bare v_exp_f32 (exp2), zero muls/negs in
//     loop, -3 dep-chain links. Saturation exact (2^-inf=0, 2^+inf=inf).
// LDS: wlds 96K | abuf 16K | fcwl 8K | oring 4K = 124 KB.
__global__ __launch_bounds__(1024, 4) void gru_rec(
        const short* __restrict__ xg, size_t plane,
        const float* __restrict__ w_hh,
        const float* __restrict__ b_hh,
        const float* __restrict__ fc_w,
        const float* __restrict__ fc_b,
        const short* __restrict__ wnsc,
        float* __restrict__ out,
        float* __restrict__ hcar,
        int t0, int ns)
{
    __shared__ short wlds[49152];    // n-gate W_hh (x -2log2e): 16 jb x 6 x 512
    __shared__ short abuf[8192];     // h staging, 2 x 8 chunks x 512
    __shared__ short fcwl[4096];     // fc_w B-frags (col 0 only), 8 x 512
    __shared__ float oring[1024];    // out ring, 2 x 32 steps x 16 batch

    const int tid = threadIdx.x, wv = tid >> 6, lane = tid & 63;
    const int nn = lane & 15, q = lane >> 4;
    const int bc = blockIdx.x, bbase = bc * 16;

    // ---- one-time staging (weights pre-scaled for exp2) ----
    bf16x8 wr[8], wz[8];
    #pragma unroll
    for (int c = 0; c < 8; ++c)
        wr[c] = ldfrag_s(w_hh + (0 * NH + wv * 16 + nn) * NH + c * 32 + q * 8, SRZ);
    #pragma unroll
    for (int c = 0; c < 8; ++c)
        wz[c] = ldfrag_s(w_hh + (1 * NH + wv * 16 + nn) * NH + c * 32 + q * 8, SRZ);
    #pragma unroll
    for (int c = 0; c < 6; ++c) {    // chunks 0-5 -> LDS; 6-7 stream from L2
        bf16x8 f = ldfrag_s(w_hh + (2 * NH + wv * 16 + nn) * NH + c * 32 + q * 8, SN);
        *(bf16x8*)(wlds + (wv * 6 + c) * 512 + lane * 8) = f;
    }
    if (wv < 8) {                    // fc B-frag: col nn==0 = fc_w, else 0 (UNSCALED)
        bf16x8 f = 0;
        if (nn == 0) f = ldfrag(fc_w + wv * 32 + q * 8);
        *(bf16x8*)(fcwl + wv * 512 + lane * 8) = f;
    }
    const float bhn = SN * b_hh[2 * NH + wv * 16 + nn];
    const float fcb = fc_b[0];
    const short* wnp = wnsc + ((size_t)wv * 64 + lane) * 16;  // loop-invariant

    // ---- h init ----
    f32x4 hp = {0.f, 0.f, 0.f, 0.f};
    if (t0 == 0) {
        ((int4*)abuf)[tid & 511] = make_int4(0, 0, 0, 0);
    } else {
        #pragma unroll
        for (int m = 0; m < 4; ++m)
            hp[m] = hcar[(size_t)(bbase + q * 4 + m) * NH + wv * 16 + nn];
        const int f = tid * 4, b = f >> 8, k0 = f & 255;
        float4 v = *(const float4*)(hcar + (size_t)(bbase + b) * NH + k0);
        bf16x4 s; s[0] = (short)f2bf(v.x); s[1] = (short)f2bf(v.y);
        s[2] = (short)f2bf(v.z); s[3] = (short)f2bf(v.w);
        *(bf16x4*)(abuf + (k0 >> 5) * 512 + (((k0 >> 3) & 3) * 16 + b) * 8 + (k0 & 7)) = s;
    }

    const int j = wv * 16 + nn;
    const int koff = (j >> 5) * 512 + ((j >> 3) & 3) * 128 + (j & 7) + q * 32;
    const short* xgp = xg + ((size_t)(bc * 16 + wv) * 64 + lane) * 4;
    __syncthreads();

    for (int t = 0; t < ns; ++t) {
        const int cur = t & 1, nxt = cur ^ 1;

        // wn67 stream from L2 scratch: issued first, consumed in phase 1
        bf16x8 wn6g = *(const bf16x8*)(wnp);
        bf16x8 wn7g = *(const bf16x8*)(wnp + 8);

        int2 gx = *(const int2*)(xgp);
        int2 gz = *(const int2*)(xgp + plane);
        int2 gn = *(const int2*)(xgp + 2 * plane);
        xgp += 16384;

        // out flush, once per 32 steps (slots all >=1 barrier old)
        if ((t & 31) == 1 && t >= 33 && tid < 512) {
            const int s0 = t - 33;
            out[((size_t)(t0 + s0 + (tid >> 4))) * NB + bbase + (tid & 15)] =
                oring[(((s0 >> 5) & 1) << 9) + (tid >> 4) * 16 + (tid & 15)];
        }

        const bool isfc = (t > 0) && (wv == (t & 15));
        f32x4 ar = {0.f,0.f,0.f,0.f};
        f32x4 an = { bhn, bhn, bhn, bhn };   // SN*b_hh(n) folded into C-init
        f32x4 afc = {0.f,0.f,0.f,0.f};
        const short* ab = abuf + cur * 4096;

        // ---- phase 1: ar + an chains (r and n feed the long dep chain) ----
        #pragma unroll
        for (int c = 0; c < 8; ++c) {
            bf16x8 av = *(const bf16x8*)(ab + c * 512 + lane * 8);
            ar = mfma16(av, wr[c], ar);
            bf16x8 wnf = (c < 6) ? *(const bf16x8*)(wlds + (wv * 6 + c) * 512 + lane * 8)
                                 : (c == 6 ? wn6g : wn7g);
            an = mfma16(av, wnf, an);
            if (isfc) {   // rotating wave: FC(h_{t-1}) rides on the same av
                bf16x8 ff = *(const bf16x8*)(fcwl + c * 512 + lane * 8);
                afc = mfma16(av, ff, afc);
            }
        }
        if (isfc && nn == 0) {
            const int s = t - 1;
            f32x4 v;
            #pragma unroll
            for (int m = 0; m < 4; ++m) v[m] = afc[m] + fcb;
            *(f32x4*)(oring + (((s >> 5) & 1) << 9) + ((s & 31) << 4) + q * 4) = v;
        }

        // ---- phase 2: az chain (independent) issued right before the r/tanh
        // trans block -- in-order wave issue interleaves MFMA with VALU/trans,
        // so the matrix pipe runs under the transcendental chain.
        f32x4 az = {0.f,0.f,0.f,0.f};
        #pragma unroll
        for (int c = 0; c < 8; ++c) {
            bf16x8 av = *(const bf16x8*)(ab + c * 512 + lane * 8);
            az = mfma16(av, wz[c], az);
        }

        // r-sigmoid + tanh (no az dependency). All inputs pre-scaled:
        // ar+xr = -log2e*rx -> 2^() = e^-rx; yn = -2log2e*y -> 2^() = e^-2y.
        const f32x2 one2 = {1.f, 1.f};
        f32x2 nt2[2];
        #pragma unroll
        for (int p = 0; p < 2; ++p) {
            f32x2 arp = {ar[2*p], ar[2*p+1]};
            f32x2 anp = {an[2*p], an[2*p+1]};
            f32x2 tr = arp + bfup2(p ? gx.y : gx.x);        // v_pk_add
            f32x2 er = {ex2(tr[0]), ex2(tr[1])};            // e^-rx
            f32x2 dr = er + one2;
            f32x2 rr = {fast_rcp(dr[0]), fast_rcp(dr[1])};  // r
            f32x2 yn = __builtin_elementwise_fma(rr, anp, bfup2(p ? gn.y : gn.x));
            f32x2 en = {ex2(yn[0]), ex2(yn[1])};            // e^-2y
            f32x2 dn = en + one2;
            f32x2 qn = {fast_rcp(dn[0]), fast_rcp(dn[1])};
            nt2[p] = __builtin_elementwise_fma((f32x2){2.f,2.f}, qn,
                                               (f32x2){-1.f,-1.f});  // tanh
        }

        // ---- tail: z-sigmoid + blend + h write ----
        short* hw = abuf + nxt * 4096 + koff;
        #pragma unroll
        for (int p = 0; p < 2; ++p) {
            f32x2 azp = {az[2*p], az[2*p+1]};
            f32x2 hpp = {hp[2*p], hp[2*p+1]};
            f32x2 tz = azp + bfup2(p ? gz.y : gz.x);
            f32x2 ez = {ex2(tz[0]), ex2(tz[1])};
            f32x2 dz = ez + one2;
            f32x2 zz = {fast_rcp(dz[0]), fast_rcp(dz[1])};  // z
            f32x2 df = hpp - nt2[p];
            f32x2 h2 = __builtin_elementwise_fma(zz, df, nt2[p]);
            hp[2*p] = h2[0]; hp[2*p+1] = h2[1];
            const int pk = cvtpk_bf16(h2[0], h2[1]);        // RNE bf16 pair
            hw[(2*p) * 8]     = (short)(pk & 0xffff);
            hw[(2*p + 1) * 8] = (short)(((unsigned)pk) >> 16);
        }
        __syncthreads();   // single per-step barrier
    }

    // ---- tail: FC for step ns-1, flush last 32, h carry ----
    if (wv == 0) {
        const short* ab = abuf + (ns & 1) * 4096;
        f32x4 afc = {0.f, 0.f, 0.f, 0.f};
        #pragma unroll
        for (int c = 0; c < 8; ++c)
            afc = mfma16(*(const bf16x8*)(ab + c * 512 + lane * 8),
                         *(const bf16x8*)(fcwl + c * 512 + lane * 8), afc);
        if (nn == 0) {
            const int s = ns - 1;
            f32x4 v;
            #pragma unroll
            for (int m = 0; m < 4; ++m) v[m] = afc[m] + fcb;
            *(f32x4*)(oring + (((s >> 5) & 1) << 9) + ((s & 31) << 4) + q * 4) = v;
        }
    }
    __syncthreads();
    if (tid < 512) {
        const int s0 = ns - 32;
        out[((size_t)(t0 + s0 + (tid >> 4))) * NB + bbase + (tid & 15)] =
            oring[(((s0 >> 5) & 1) << 9) + (tid >> 4) * 16 + (tid & 15)];
    }
    #pragma unroll
    for (int m = 0; m < 4; ++m)
        hcar[(size_t)(bbase + q * 4 + m) * NH + wv * 16 + nn] = hp[m];
}

extern "C" void kernel_launch(void* const* d_in, const int* in_sizes, int n_in,
                              void* d_out, int out_size, void* d_ws, size_t ws_size,
                              hipStream_t stream) {
    (void)in_sizes; (void)n_in; (void)out_size;
    const float* x    = (const float*)d_in[0];
    const float* w_ih = (const float*)d_in[1];
    const float* w_hh = (const float*)d_in[2];
    const float* b_ih = (const float*)d_in[3];
    const float* b_hh = (const float*)d_in[4];
    const float* fc_w = (const float*)d_in[5];
    const float* fc_b = (const float*)d_in[6];
    float* out  = (float*)d_out;
    float* hcar = (float*)d_ws;                       // 64 KB h carry
    short* wnsc = (short*)((char*)d_ws + 65536);      // 32 KB wn67 bf16 scratch
    short* xg   = (short*)((char*)d_ws + 65536 + 32768);  // 3 gate planes

    const size_t per_step = (size_t)NB * 3 * NH * 2;  // 98304 B / step
    long avail = (long)ws_size - 65536 - 32768;
    int spc = 64;
    if (avail >= (long)per_step * 64) {
        spc = (int)((avail / (long)per_step) / 64) * 64;
        if (spc > SEQ) spc = SEQ;
    }
    for (int t0 = 0; t0 < SEQ; t0 += spc) {
        int ns = (SEQ - t0 < spc) ? (SEQ - t0) : spc;
        size_t plane = (size_t)spc * 16384;           // shorts per gate plane
        xg_pre<<<dim3(2048), dim3(1024), 0, stream>>>(x, w_ih, w_hh, b_ih, b_hh,
                                                      xg, wnsc, plane, t0, ns);
        gru_rec<<<dim3(4), dim3(1024), 0, stream>>>(xg, plane, w_hh, b_hh,
                                                    fc_w, fc_b, wnsc, out, hcar,
                                                    t0, ns);
    }
}

// Round 11
// 8790.858 us; speedup vs baseline: 1.6115x; 1.6115x over previous
//
#include <hip/hip_runtime.h>

#define SEQ  4096
#define NB   64
#define NI   64
#define NH   256

typedef short  bf16x8 __attribute__((ext_vector_type(8)));
typedef short  bf16x4 __attribute__((ext_vector_type(4)));
typedef float  f32x4  __attribute__((ext_vector_type(4)));
typedef float  f32x2  __attribute__((ext_vector_type(2)));

#define SRZ (-1.4426950408889634f)   /* -log2(e):  exp(-x) = 2^(SRZ*x) */
#define SN  (-2.8853900817779268f)   /* -2log2(e): exp(-2y) = 2^(SN*y) */

__device__ __forceinline__ unsigned short f2bf(float f) {
    union { float f; unsigned u; } v; v.f = f;
    return (unsigned short)((v.u + 0x7fffu + ((v.u >> 16) & 1u)) >> 16);
}
__device__ __forceinline__ float bflo(int p) {
    union { int i; float f; } u; u.i = p << 16; return u.f;
}
__device__ __forceinline__ float bfhi(int p) {
    union { int i; float f; } u; u.i = p & 0xffff0000; return u.f;
}
__device__ __forceinline__ float fast_rcp(float x) { return __builtin_amdgcn_rcpf(x); }
__device__ __forceinline__ float ex2(float x) { return __builtin_amdgcn_exp2f(x); }
// packed bf16 convert (RNE) -- same rounding as f2bf, 1 inst for 2 values
__device__ __forceinline__ int cvtpk_bf16(float lo, float hi) {
    int r; asm("v_cvt_pk_bf16_f32 %0, %1, %2" : "=v"(r) : "v"(lo), "v"(hi));
    return r;
}
// two packed bf16 (lo16,hi16 of p) -> f32x2
__device__ __forceinline__ f32x2 bfup2(int p) {
    f32x2 r; r[0] = bflo(p); r[1] = bfhi(p); return r;
}
__device__ __forceinline__ f32x4 mfma16(bf16x8 a, bf16x8 b, f32x4 c) {
    return __builtin_amdgcn_mfma_f32_16x16x32_bf16(a, b, c, 0, 0, 0);
}
__device__ __forceinline__ bf16x8 ldfrag(const float* p) {
    float4 a = *(const float4*)p;
    float4 b = *(const float4*)(p + 4);
    bf16x8 r;
    r[0] = (short)f2bf(a.x); r[1] = (short)f2bf(a.y);
    r[2] = (short)f2bf(a.z); r[3] = (short)f2bf(a.w);
    r[4] = (short)f2bf(b.x); r[5] = (short)f2bf(b.y);
    r[6] = (short)f2bf(b.z); r[7] = (short)f2bf(b.w);
    return r;
}
// scaled variant: weights pre-scaled so loop transcendentals are bare v_exp
__device__ __forceinline__ bf16x8 ldfrag_s(const float* p, float s) {
    float4 a = *(const float4*)p;
    float4 b = *(const float4*)(p + 4);
    bf16x8 r;
    r[0] = (short)f2bf(a.x*s); r[1] = (short)f2bf(a.y*s);
    r[2] = (short)f2bf(a.z*s); r[3] = (short)f2bf(a.w*s);
    r[4] = (short)f2bf(b.x*s); r[5] = (short)f2bf(b.y*s);
    r[6] = (short)f2bf(b.z*s); r[7] = (short)f2bf(b.w*s);
    return r;
}

// ============ xg precompute + one-time wn67 bf16 scratch ====================
// Gate planes pre-scaled: r,z by -log2e; n by -2log2e (exp2 folding --
// numerics validated by R10's pass, absmax identical to unscaled R9).
__global__ __launch_bounds__(1024) void xg_pre(
        const float* __restrict__ x, const float* __restrict__ w_ih,
        const float* __restrict__ w_hh,
        const float* __restrict__ b_ih, const float* __restrict__ b_hh,
        short* __restrict__ xg, short* __restrict__ wnsc,
        size_t plane, int t0, int ns)
{
    const int tid = threadIdx.x, wv = tid >> 6, lane = tid & 63;
    const int nn = lane & 15, q = lane >> 4;
    const int jb = wv;

    // one-time: (-2log2e)-scaled n-gate W_hh chunks 6-7 -> global scratch (32KB)
    if (t0 == 0 && blockIdx.x == 0) {
        bf16x8 f6 = ldfrag_s(w_hh + (2 * NH + wv * 16 + nn) * NH + 6 * 32 + q * 8, SN);
        bf16x8 f7 = ldfrag_s(w_hh + (2 * NH + wv * 16 + nn) * NH + 7 * 32 + q * 8, SN);
        *(bf16x8*)(wnsc + ((size_t)wv * 64 + lane) * 16)     = f6;
        *(bf16x8*)(wnsc + ((size_t)wv * 64 + lane) * 16 + 8) = f7;
    }

    bf16x8 w[3][2];
    float bias[3];
    const float sc[3] = { SRZ, SRZ, SN };
    #pragma unroll
    for (int g = 0; g < 3; ++g) {
        const int row = g * NH + jb * 16 + nn;
        w[g][0] = ldfrag(w_ih + row * NI + q * 8);
        w[g][1] = ldfrag(w_ih + row * NI + 32 + q * 8);
        bias[g] = b_ih[row] + (g < 2 ? b_hh[row] : 0.f);
    }

    const int NT = ns * 4;                       // 16-row tiles in chunk
    for (int rt = blockIdx.x; rt < NT; rt += gridDim.x) {
        const float* xr = x + ((size_t)t0 * NB + (size_t)rt * 16 + nn) * NI + q * 8;
        bf16x8 a0 = ldfrag(xr);
        bf16x8 a1 = ldfrag(xr + 32);
        #pragma unroll
        for (int g = 0; g < 3; ++g) {
            f32x4 acc = {0.f, 0.f, 0.f, 0.f};
            acc = mfma16(a0, w[g][0], acc);
            acc = mfma16(a1, w[g][1], acc);
            bf16x4 v;
            #pragma unroll
            for (int m = 0; m < 4; ++m)
                v[m] = (short)f2bf((acc[m] + bias[g]) * sc[g]);
            *(bf16x4*)(xg + (size_t)g * plane +
                       (((size_t)rt * 16 + jb) * 64 + lane) * 4) = v;
        }
    }
}

// ============ recurrent kernel ==============================================
// R9 STRUCTURE EXACTLY (proven 4206us: single fused ar/az/an/afc MFMA chain,
// packed-f32 nonlinearity) + ONE change: exp2 folding. Weights/gates are
// pre-scaled (-log2e for r,z; -2log2e for n) so the three __expf become bare
// v_exp_f32: -12 VALU muls/wave/step and -1 dep-chain link per gate.
// R10 LESSON: do NOT split the 3-gate MFMA chain into phases -- the az-only
// chain (8 serially-dependent MFMAs + own ds_read group) added ~3000 idle
// cyc/step (9340us). The fused chain with 3 independent accumulators is the
// scheduler-friendly form. R10 DID validate exp2-folding numerics (absmax
// 0.001953125, == R9).
// LDS: wlds 96K | abuf 16K | fcwl 8K | oring 4K = 124 KB.
__global__ __launch_bounds__(1024, 4) void gru_rec(
        const short* __restrict__ xg, size_t plane,
        const float* __restrict__ w_hh,
        const float* __restrict__ b_hh,
        const float* __restrict__ fc_w,
        const float* __restrict__ fc_b,
        const short* __restrict__ wnsc,
        float* __restrict__ out,
        float* __restrict__ hcar,
        int t0, int ns)
{
    __shared__ short wlds[49152];    // n-gate W_hh (x -2log2e): 16 jb x 6 x 512
    __shared__ short abuf[8192];     // h staging, 2 x 8 chunks x 512
    __shared__ short fcwl[4096];     // fc_w B-frags (col 0 only), 8 x 512
    __shared__ float oring[1024];    // out ring, 2 x 32 steps x 16 batch

    const int tid = threadIdx.x, wv = tid >> 6, lane = tid & 63;
    const int nn = lane & 15, q = lane >> 4;
    const int bc = blockIdx.x, bbase = bc * 16;

    // ---- one-time staging (weights pre-scaled for exp2) ----
    bf16x8 wr[8], wz[8];
    #pragma unroll
    for (int c = 0; c < 8; ++c)
        wr[c] = ldfrag_s(w_hh + (0 * NH + wv * 16 + nn) * NH + c * 32 + q * 8, SRZ);
    #pragma unroll
    for (int c = 0; c < 8; ++c)
        wz[c] = ldfrag_s(w_hh + (1 * NH + wv * 16 + nn) * NH + c * 32 + q * 8, SRZ);
    #pragma unroll
    for (int c = 0; c < 6; ++c) {    // chunks 0-5 -> LDS; 6-7 stream from L2
        bf16x8 f = ldfrag_s(w_hh + (2 * NH + wv * 16 + nn) * NH + c * 32 + q * 8, SN);
        *(bf16x8*)(wlds + (wv * 6 + c) * 512 + lane * 8) = f;
    }
    if (wv < 8) {                    // fc B-frag: col nn==0 = fc_w, else 0 (UNSCALED)
        bf16x8 f = 0;
        if (nn == 0) f = ldfrag(fc_w + wv * 32 + q * 8);
        *(bf16x8*)(fcwl + wv * 512 + lane * 8) = f;
    }
    const float bhn = SN * b_hh[2 * NH + wv * 16 + nn];
    const float fcb = fc_b[0];
    const short* wnp = wnsc + ((size_t)wv * 64 + lane) * 16;  // loop-invariant

    // ---- h init ----
    f32x4 hp = {0.f, 0.f, 0.f, 0.f};
    if (t0 == 0) {
        ((int4*)abuf)[tid & 511] = make_int4(0, 0, 0, 0);
    } else {
        #pragma unroll
        for (int m = 0; m < 4; ++m)
            hp[m] = hcar[(size_t)(bbase + q * 4 + m) * NH + wv * 16 + nn];
        const int f = tid * 4, b = f >> 8, k0 = f & 255;
        float4 v = *(const float4*)(hcar + (size_t)(bbase + b) * NH + k0);
        bf16x4 s; s[0] = (short)f2bf(v.x); s[1] = (short)f2bf(v.y);
        s[2] = (short)f2bf(v.z); s[3] = (short)f2bf(v.w);
        *(bf16x4*)(abuf + (k0 >> 5) * 512 + (((k0 >> 3) & 3) * 16 + b) * 8 + (k0 & 7)) = s;
    }

    const int j = wv * 16 + nn;
    const int koff = (j >> 5) * 512 + ((j >> 3) & 3) * 128 + (j & 7) + q * 32;
    const short* xgp = xg + ((size_t)(bc * 16 + wv) * 64 + lane) * 4;
    __syncthreads();

    for (int t = 0; t < ns; ++t) {
        const int cur = t & 1, nxt = cur ^ 1;

        // wn67 stream from L2 scratch: issued first, consumed at chain end
        bf16x8 wn6g = *(const bf16x8*)(wnp);
        bf16x8 wn7g = *(const bf16x8*)(wnp + 8);

        int2 gx = *(const int2*)(xgp);
        int2 gz = *(const int2*)(xgp + plane);
        int2 gn = *(const int2*)(xgp + 2 * plane);
        xgp += 16384;

        // out flush, once per 32 steps (slots all >=1 barrier old)
        if ((t & 31) == 1 && t >= 33 && tid < 512) {
            const int s0 = t - 33;
            out[((size_t)(t0 + s0 + (tid >> 4))) * NB + bbase + (tid & 15)] =
                oring[(((s0 >> 5) & 1) << 9) + (tid >> 4) * 16 + (tid & 15)];
        }

        const bool isfc = (t > 0) && (wv == (t & 15));
        f32x4 ar = {0.f,0.f,0.f,0.f}, az = {0.f,0.f,0.f,0.f};
        f32x4 an = { bhn, bhn, bhn, bhn };   // SN*b_hh(n) folded into C-init
        f32x4 afc = {0.f,0.f,0.f,0.f};
        const short* ab = abuf + cur * 4096;
        #pragma unroll
        for (int c = 0; c < 8; ++c) {
            bf16x8 av = *(const bf16x8*)(ab + c * 512 + lane * 8);
            ar = mfma16(av, wr[c], ar);
            az = mfma16(av, wz[c], az);
            bf16x8 wnf = (c < 6) ? *(const bf16x8*)(wlds + (wv * 6 + c) * 512 + lane * 8)
                                 : (c == 6 ? wn6g : wn7g);
            an = mfma16(av, wnf, an);
            if (isfc) {   // rotating wave: FC(h_{t-1}) rides on the same av
                bf16x8 ff = *(const bf16x8*)(fcwl + c * 512 + lane * 8);
                afc = mfma16(av, ff, afc);
            }
        }
        if (isfc && nn == 0) {
            const int s = t - 1;
            f32x4 v;
            #pragma unroll
            for (int m = 0; m < 4; ++m) v[m] = afc[m] + fcb;
            *(f32x4*)(oring + (((s >> 5) & 1) << 9) + ((s & 31) << 4) + q * 4) = v;
        }

        // ---- packed-f32 nonlinearity (pairs m={0,1} and m={2,3}) ----
        // all gate inputs pre-scaled: 2^(acc+xg) == e^-(raw) for r,z;
        // 2^(fma(r,an,xn)) == e^-2y for n.
        short* hw = abuf + nxt * 4096 + koff;
        const f32x2 one2 = {1.f, 1.f};
        #pragma unroll
        for (int p = 0; p < 2; ++p) {
            const int gxp = p ? gx.y : gx.x;
            const int gzp = p ? gz.y : gz.x;
            const int gnp = p ? gn.y : gn.x;
            f32x2 arp = {ar[2*p], ar[2*p+1]};
            f32x2 azp = {az[2*p], az[2*p+1]};
            f32x2 anp = {an[2*p], an[2*p+1]};
            f32x2 hpp = {hp[2*p], hp[2*p+1]};

            f32x2 tr = arp + bfup2(gxp);                    // v_pk_add
            f32x2 tz = azp + bfup2(gzp);
            f32x2 er = {ex2(tr[0]), ex2(tr[1])};            // e^-rx (bare v_exp)
            f32x2 ez = {ex2(tz[0]), ex2(tz[1])};
            f32x2 dr = er + one2, dz = ez + one2;
            f32x2 rr = {fast_rcp(dr[0]), fast_rcp(dr[1])};
            f32x2 zz = {fast_rcp(dz[0]), fast_rcp(dz[1])};
            f32x2 y  = __builtin_elementwise_fma(rr, anp, bfup2(gnp)); // v_pk_fma
            f32x2 en = {ex2(y[0]), ex2(y[1])};              // e^-2y (bare v_exp)
            f32x2 dn = en + one2;
            f32x2 qn = {fast_rcp(dn[0]), fast_rcp(dn[1])};
            f32x2 nt = __builtin_elementwise_fma((f32x2){2.f,2.f}, qn,
                                                 (f32x2){-1.f,-1.f}); // tanh
            f32x2 df = hpp - nt;                            // v_pk_add(neg)
            f32x2 h2 = __builtin_elementwise_fma(zz, df, nt);
            hp[2*p] = h2[0]; hp[2*p+1] = h2[1];
            const int pk = cvtpk_bf16(h2[0], h2[1]);        // RNE bf16 pair
            hw[(2*p) * 8]     = (short)(pk & 0xffff);
            hw[(2*p + 1) * 8] = (short)(((unsigned)pk) >> 16);
        }
        __syncthreads();   // single per-step barrier
    }

    // ---- tail: FC for step ns-1, flush last 32, h carry ----
    if (wv == 0) {
        const short* ab = abuf + (ns & 1) * 4096;
        f32x4 afc = {0.f, 0.f, 0.f, 0.f};
        #pragma unroll
        for (int c = 0; c < 8; ++c)
            afc = mfma16(*(const bf16x8*)(ab + c * 512 + lane * 8),
                         *(const bf16x8*)(fcwl + c * 512 + lane * 8), afc);
        if (nn == 0) {
            const int s = ns - 1;
            f32x4 v;
            #pragma unroll
            for (int m = 0; m < 4; ++m) v[m] = afc[m] + fcb;
            *(f32x4*)(oring + (((s >> 5) & 1) << 9) + ((s & 31) << 4) + q * 4) = v;
        }
    }
    __syncthreads();
    if (tid < 512) {
        const int s0 = ns - 32;
        out[((size_t)(t0 + s0 + (tid >> 4))) * NB + bbase + (tid & 15)] =
            oring[(((s0 >> 5) & 1) << 9) + (tid >> 4) * 16 + (tid & 15)];
    }
    #pragma unroll
    for (int m = 0; m < 4; ++m)
        hcar[(size_t)(bbase + q * 4 + m) * NH + wv * 16 + nn] = hp[m];
}

extern "C" void kernel_launch(void* const* d_in, const int* in_sizes, int n_in,
                              void* d_out, int out_size, void* d_ws, size_t ws_size,
                              hipStream_t stream) {
    (void)in_sizes; (void)n_in; (void)out_size;
    const float* x    = (const float*)d_in[0];
    const float* w_ih = (const float*)d_in[1];
    const float* w_hh = (const float*)d_in[2];
    const float* b_ih = (const float*)d_in[3];
    const float* b_hh = (const float*)d_in[4];
    const float* fc_w = (const float*)d_in[5];
    const float* fc_b = (const float*)d_in[6];
    float* out  = (float*)d_out;
    float* hcar = (float*)d_ws;                       // 64 KB h carry
    short* wnsc = (short*)((char*)d_ws + 65536);      // 32 KB wn67 bf16 scratch
    short* xg   = (short*)((char*)d_ws + 65536 + 32768);  // 3 gate planes

    const size_t per_step = (size_t)NB * 3 * NH * 2;  // 98304 B / step
    long avail = (long)ws_size - 65536 - 32768;
    int spc = 64;
    if (avail >= (long)per_step * 64) {
        spc = (int)((avail / (long)per_step) / 64) * 64;
        if (spc > SEQ) spc = SEQ;
    }
    for (int t0 = 0; t0 < SEQ; t0 += spc) {
        int ns = (SEQ - t0 < spc) ? (SEQ - t0) : spc;
        size_t plane = (size_t)spc * 16384;           // shorts per gate plane
        xg_pre<<<dim3(2048), dim3(1024), 0, stream>>>(x, w_ih, w_hh, b_ih, b_hh,
                                                      xg, wnsc, plane, t0, ns);
        gru_rec<<<dim3(4), dim3(1024), 0, stream>>>(xg, plane, w_hh, b_hh,
                                                    fc_w, fc_b, wnsc, out, hcar,
                                                    t0, ns);
    }
}

// Round 12
// 6740.589 us; speedup vs baseline: 2.1017x; 1.3042x over previous
//
#include <hip/hip_runtime.h>

#define SEQ  4096
#define NB   64
#define NI   64
#define NH   256

typedef short  bf16x8 __attribute__((ext_vector_type(8)));
typedef short  bf16x4 __attribute__((ext_vector_type(4)));
typedef float  f32x4  __attribute__((ext_vector_type(4)));
typedef float  f32x2  __attribute__((ext_vector_type(2)));

__device__ __forceinline__ unsigned short f2bf(float f) {
    union { float f; unsigned u; } v; v.f = f;
    return (unsigned short)((v.u + 0x7fffu + ((v.u >> 16) & 1u)) >> 16);
}
__device__ __forceinline__ float bflo(int p) {
    union { int i; float f; } u; u.i = p << 16; return u.f;
}
__device__ __forceinline__ float bfhi(int p) {
    union { int i; float f; } u; u.i = p & 0xffff0000; return u.f;
}
__device__ __forceinline__ float fast_rcp(float x) { return __builtin_amdgcn_rcpf(x); }
__device__ __forceinline__ float sigm(float x) { return fast_rcp(1.f + __expf(-x)); }
// clamp-free tanh: 2/(1+e^{-2y}) - 1 (saturates correctly at +-inf, no NaN path)
__device__ __forceinline__ float tanh_(float y) {
    float e = __expf(-2.f * y);
    return fmaf(2.f, fast_rcp(1.f + e), -1.f);
}
// packed bf16 convert (RNE) -- same rounding as f2bf, 1 inst for 2 values
__device__ __forceinline__ int cvtpk_bf16(float lo, float hi) {
    int r; asm("v_cvt_pk_bf16_f32 %0, %1, %2" : "=v"(r) : "v"(lo), "v"(hi));
    return r;
}
// two packed bf16 (lo16,hi16 of p) -> f32x2
__device__ __forceinline__ f32x2 bfup2(int p) {
    f32x2 r; r[0] = bflo(p); r[1] = bfhi(p); return r;
}
__device__ __forceinline__ f32x4 mfma16(bf16x8 a, bf16x8 b, f32x4 c) {
    return __builtin_amdgcn_mfma_f32_16x16x32_bf16(a, b, c, 0, 0, 0);
}
__device__ __forceinline__ bf16x8 ldfrag(const float* p) {
    float4 a = *(const float4*)p;
    float4 b = *(const float4*)(p + 4);
    bf16x8 r;
    r[0] = (short)f2bf(a.x); r[1] = (short)f2bf(a.y);
    r[2] = (short)f2bf(a.z); r[3] = (short)f2bf(a.w);
    r[4] = (short)f2bf(b.x); r[5] = (short)f2bf(b.y);
    r[6] = (short)f2bf(b.z); r[7] = (short)f2bf(b.w);
    return r;
}

// ============ xg precompute + one-time wn67 bf16 scratch ====================
__global__ __launch_bounds__(1024) void xg_pre(
        const float* __restrict__ x, const float* __restrict__ w_ih,
        const float* __restrict__ w_hh,
        const float* __restrict__ b_ih, const float* __restrict__ b_hh,
        short* __restrict__ xg, short* __restrict__ wnsc,
        size_t plane, int t0, int ns)
{
    const int tid = threadIdx.x, wv = tid >> 6, lane = tid & 63;
    const int nn = lane & 15, q = lane >> 4;
    const int jb = wv;

    // one-time: bf16-converted n-gate W_hh chunks 6-7 -> global scratch (32KB)
    if (t0 == 0 && blockIdx.x == 0) {
        bf16x8 f6 = ldfrag(w_hh + (2 * NH + wv * 16 + nn) * NH + 6 * 32 + q * 8);
        bf16x8 f7 = ldfrag(w_hh + (2 * NH + wv * 16 + nn) * NH + 7 * 32 + q * 8);
        *(bf16x8*)(wnsc + ((size_t)wv * 64 + lane) * 16)     = f6;
        *(bf16x8*)(wnsc + ((size_t)wv * 64 + lane) * 16 + 8) = f7;
    }

    bf16x8 w[3][2];
    float bias[3];
    #pragma unroll
    for (int g = 0; g < 3; ++g) {
        const int row = g * NH + jb * 16 + nn;
        w[g][0] = ldfrag(w_ih + row * NI + q * 8);
        w[g][1] = ldfrag(w_ih + row * NI + 32 + q * 8);
        bias[g] = b_ih[row] + (g < 2 ? b_hh[row] : 0.f);
    }

    const int NT = ns * 4;                       // 16-row tiles in chunk
    for (int rt = blockIdx.x; rt < NT; rt += gridDim.x) {
        const float* xr = x + ((size_t)t0 * NB + (size_t)rt * 16 + nn) * NI + q * 8;
        bf16x8 a0 = ldfrag(xr);
        bf16x8 a1 = ldfrag(xr + 32);
        #pragma unroll
        for (int g = 0; g < 3; ++g) {
            f32x4 acc = {0.f, 0.f, 0.f, 0.f};
            acc = mfma16(a0, w[g][0], acc);
            acc = mfma16(a1, w[g][1], acc);
            bf16x4 v;
            #pragma unroll
            for (int m = 0; m < 4; ++m) v[m] = (short)f2bf(acc[m] + bias[g]);
            *(bf16x4*)(xg + (size_t)g * plane +
                       (((size_t)rt * 16 + jb) * 64 + lane) * 4) = v;
        }
    }
}

// ============ recurrent kernel ==============================================
// R9 VERBATIM -- the proven best (gru_rec 4206us, bench 6725us).
// Session law (11 rounds): this loop is scheduling-fragile. Busy cycles are
// invariant across ALL variants (MFMA ~1020, VALU ~1350 cyc/step/SIMD); every
// structural deviation added only idle: R1 wave-split +1300, R3 all-regs
// +5600 (remat), R5 divergent ds_read +900, R10 gate-split +3600, R11 exp2
// folding +1000 (bare v_exp trans hazard / scheduler constraint). The step is
// the SERIAL SUM of the MFMA phase and the VALU/trans phase (barrier-aligned
// waves, global h(t)->gates(t+1) dependency) -- only in-pattern instruction
// reductions (R4 tanh/bias fold, R9 packed-f32 + cvt_pk) have landed.
// Structure: 16 waves; wr/wz in regs; wn c0-5 in LDS, c6-7 streamed from L2
// scratch (issued loop-top, consumed chain-end); FC rides a rotating wave;
// packed-f32 nonlinearity; single per-step barrier.
// LDS: wlds 96K | abuf 16K | fcwl 8K | oring 4K = 124 KB.
__global__ __launch_bounds__(1024, 4) void gru_rec(
        const short* __restrict__ xg, size_t plane,
        const float* __restrict__ w_hh,
        const float* __restrict__ b_hh,
        const float* __restrict__ fc_w,
        const float* __restrict__ fc_b,
        const short* __restrict__ wnsc,
        float* __restrict__ out,
        float* __restrict__ hcar,
        int t0, int ns)
{
    __shared__ short wlds[49152];    // n-gate W_hh: 16 jb x 6 chunks x 512
    __shared__ short abuf[8192];     // h staging, 2 x 8 chunks x 512
    __shared__ short fcwl[4096];     // fc_w B-frags (col 0 only), 8 x 512
    __shared__ float oring[1024];    // out ring, 2 x 32 steps x 16 batch

    const int tid = threadIdx.x, wv = tid >> 6, lane = tid & 63;
    const int nn = lane & 15, q = lane >> 4;
    const int bc = blockIdx.x, bbase = bc * 16;

    // ---- one-time staging ----
    bf16x8 wr[8], wz[8];
    #pragma unroll
    for (int c = 0; c < 8; ++c)
        wr[c] = ldfrag(w_hh + (0 * NH + wv * 16 + nn) * NH + c * 32 + q * 8);
    #pragma unroll
    for (int c = 0; c < 8; ++c)
        wz[c] = ldfrag(w_hh + (1 * NH + wv * 16 + nn) * NH + c * 32 + q * 8);
    #pragma unroll
    for (int c = 0; c < 6; ++c) {    // chunks 0-5 -> LDS; 6-7 stream from L2
        bf16x8 f = ldfrag(w_hh + (2 * NH + wv * 16 + nn) * NH + c * 32 + q * 8);
        *(bf16x8*)(wlds + (wv * 6 + c) * 512 + lane * 8) = f;
    }
    if (wv < 8) {                    // fc B-frag: col nn==0 = fc_w, else 0
        bf16x8 f = 0;
        if (nn == 0) f = ldfrag(fc_w + wv * 32 + q * 8);
        *(bf16x8*)(fcwl + wv * 512 + lane * 8) = f;
    }
    const float bhn = b_hh[2 * NH + wv * 16 + nn];
    const float fcb = fc_b[0];
    const short* wnp = wnsc + ((size_t)wv * 64 + lane) * 16;  // loop-invariant

    // ---- h init ----
    f32x4 hp = {0.f, 0.f, 0.f, 0.f};
    if (t0 == 0) {
        ((int4*)abuf)[tid & 511] = make_int4(0, 0, 0, 0);
    } else {
        #pragma unroll
        for (int m = 0; m < 4; ++m)
            hp[m] = hcar[(size_t)(bbase + q * 4 + m) * NH + wv * 16 + nn];
        const int f = tid * 4, b = f >> 8, k0 = f & 255;
        float4 v = *(const float4*)(hcar + (size_t)(bbase + b) * NH + k0);
        bf16x4 s; s[0] = (short)f2bf(v.x); s[1] = (short)f2bf(v.y);
        s[2] = (short)f2bf(v.z); s[3] = (short)f2bf(v.w);
        *(bf16x4*)(abuf + (k0 >> 5) * 512 + (((k0 >> 3) & 3) * 16 + b) * 8 + (k0 & 7)) = s;
    }

    const int j = wv * 16 + nn;
    const int koff = (j >> 5) * 512 + ((j >> 3) & 3) * 128 + (j & 7) + q * 32;
    const short* xgp = xg + ((size_t)(bc * 16 + wv) * 64 + lane) * 4;
    __syncthreads();

    for (int t = 0; t < ns; ++t) {
        const int cur = t & 1, nxt = cur ^ 1;

        // wn67 stream from L2 scratch: issued first, consumed at chain end
        bf16x8 wn6g = *(const bf16x8*)(wnp);
        bf16x8 wn7g = *(const bf16x8*)(wnp + 8);

        int2 gx = *(const int2*)(xgp);
        int2 gz = *(const int2*)(xgp + plane);
        int2 gn = *(const int2*)(xgp + 2 * plane);
        xgp += 16384;

        // out flush, once per 32 steps (slots all >=1 barrier old)
        if ((t & 31) == 1 && t >= 33 && tid < 512) {
            const int s0 = t - 33;
            out[((size_t)(t0 + s0 + (tid >> 4))) * NB + bbase + (tid & 15)] =
                oring[(((s0 >> 5) & 1) << 9) + (tid >> 4) * 16 + (tid & 15)];
        }

        const bool isfc = (t > 0) && (wv == (t & 15));
        f32x4 ar = {0.f,0.f,0.f,0.f}, az = {0.f,0.f,0.f,0.f};
        f32x4 an = { bhn, bhn, bhn, bhn };   // b_hh(n) folded into C-init
        f32x4 afc = {0.f,0.f,0.f,0.f};
        const short* ab = abuf + cur * 4096;
        #pragma unroll
        for (int c = 0; c < 8; ++c) {
            bf16x8 av = *(const bf16x8*)(ab + c * 512 + lane * 8);
            ar = mfma16(av, wr[c], ar);
            az = mfma16(av, wz[c], az);
            bf16x8 wnf = (c < 6) ? *(const bf16x8*)(wlds + (wv * 6 + c) * 512 + lane * 8)
                                 : (c == 6 ? wn6g : wn7g);
            an = mfma16(av, wnf, an);
            if (isfc) {   // rotating wave: FC(h_{t-1}) rides on the same av
                bf16x8 ff = *(const bf16x8*)(fcwl + c * 512 + lane * 8);
                afc = mfma16(av, ff, afc);
            }
        }
        if (isfc && nn == 0) {
            const int s = t - 1;
            f32x4 v;
            #pragma unroll
            for (int m = 0; m < 4; ++m) v[m] = afc[m] + fcb;
            *(f32x4*)(oring + (((s >> 5) & 1) << 9) + ((s & 31) << 4) + q * 4) = v;
        }

        // ---- packed-f32 nonlinearity (pairs m={0,1} and m={2,3}) ----
        short* hw = abuf + nxt * 4096 + koff;
        const f32x2 one2 = {1.f, 1.f};
        #pragma unroll
        for (int p = 0; p < 2; ++p) {
            const int gxp = p ? gx.y : gx.x;
            const int gzp = p ? gz.y : gz.x;
            const int gnp = p ? gn.y : gn.x;
            f32x2 arp = {ar[2*p], ar[2*p+1]};
            f32x2 azp = {az[2*p], az[2*p+1]};
            f32x2 anp = {an[2*p], an[2*p+1]};
            f32x2 hpp = {hp[2*p], hp[2*p+1]};

            f32x2 tr = arp + bfup2(gxp);                    // v_pk_add
            f32x2 tz = azp + bfup2(gzp);
            f32x2 er = {__expf(-tr[0]), __expf(-tr[1])};    // trans (scalar)
            f32x2 ez = {__expf(-tz[0]), __expf(-tz[1])};
            f32x2 dr = er + one2, dz = ez + one2;
            f32x2 rr = {fast_rcp(dr[0]), fast_rcp(dr[1])};
            f32x2 zz = {fast_rcp(dz[0]), fast_rcp(dz[1])};
            f32x2 y  = __builtin_elementwise_fma(rr, anp, bfup2(gnp)); // v_pk_fma
            f32x2 en = {__expf(-2.f*y[0]), __expf(-2.f*y[1])};
            f32x2 dn = en + one2;
            f32x2 qn = {fast_rcp(dn[0]), fast_rcp(dn[1])};
            f32x2 nt = __builtin_elementwise_fma((f32x2){2.f,2.f}, qn,
                                                 (f32x2){-1.f,-1.f}); // 2q-1
            f32x2 df = hpp - nt;                            // v_pk_add(neg)
            f32x2 h2 = __builtin_elementwise_fma(zz, df, nt);
            hp[2*p] = h2[0]; hp[2*p+1] = h2[1];
            const int pk = cvtpk_bf16(h2[0], h2[1]);        // RNE bf16 pair
            hw[(2*p) * 8]     = (short)(pk & 0xffff);
            hw[(2*p + 1) * 8] = (short)(((unsigned)pk) >> 16);
        }
        __syncthreads();   // single per-step barrier
    }

    // ---- tail: FC for step ns-1, flush last 32, h carry ----
    if (wv == 0) {
        const short* ab = abuf + (ns & 1) * 4096;
        f32x4 afc = {0.f, 0.f, 0.f, 0.f};
        #pragma unroll
        for (int c = 0; c < 8; ++c)
            afc = mfma16(*(const bf16x8*)(ab + c * 512 + lane * 8),
                         *(const bf16x8*)(fcwl + c * 512 + lane * 8), afc);
        if (nn == 0) {
            const int s = ns - 1;
            f32x4 v;
            #pragma unroll
            for (int m = 0; m < 4; ++m) v[m] = afc[m] + fcb;
            *(f32x4*)(oring + (((s >> 5) & 1) << 9) + ((s & 31) << 4) + q * 4) = v;
        }
    }
    __syncthreads();
    if (tid < 512) {
        const int s0 = ns - 32;
        out[((size_t)(t0 + s0 + (tid >> 4))) * NB + bbase + (tid & 15)] =
            oring[(((s0 >> 5) & 1) << 9) + (tid >> 4) * 16 + (tid & 15)];
    }
    #pragma unroll
    for (int m = 0; m < 4; ++m)
        hcar[(size_t)(bbase + q * 4 + m) * NH + wv * 16 + nn] = hp[m];
}

extern "C" void kernel_launch(void* const* d_in, const int* in_sizes, int n_in,
                              void* d_out, int out_size, void* d_ws, size_t ws_size,
                              hipStream_t stream) {
    (void)in_sizes; (void)n_in; (void)out_size;
    const float* x    = (const float*)d_in[0];
    const float* w_ih = (const float*)d_in[1];
    const float* w_hh = (const float*)d_in[2];
    const float* b_ih = (const float*)d_in[3];
    const float* b_hh = (const float*)d_in[4];
    const float* fc_w = (const float*)d_in[5];
    const float* fc_b = (const float*)d_in[6];
    float* out  = (float*)d_out;
    float* hcar = (float*)d_ws;                       // 64 KB h carry
    short* wnsc = (short*)((char*)d_ws + 65536);      // 32 KB wn67 bf16 scratch
    short* xg   = (short*)((char*)d_ws + 65536 + 32768);  // 3 gate planes

    const size_t per_step = (size_t)NB * 3 * NH * 2;  // 98304 B / step
    long avail = (long)ws_size - 65536 - 32768;
    int spc = 64;
    if (avail >= (long)per_step * 64) {
        spc = (int)((avail / (long)per_step) / 64) * 64;
        if (spc > SEQ) spc = SEQ;
    }
    for (int t0 = 0; t0 < SEQ; t0 += spc) {
        int ns = (SEQ - t0 < spc) ? (SEQ - t0) : spc;
        size_t plane = (size_t)spc * 16384;           // shorts per gate plane
        xg_pre<<<dim3(2048), dim3(1024), 0, stream>>>(x, w_ih, w_hh, b_ih, b_hh,
                                                      xg, wnsc, plane, t0, ns);
        gru_rec<<<dim3(4), dim3(1024), 0, stream>>>(xg, plane, w_hh, b_hh,
                                                    fc_w, fc_b, wnsc, out, hcar,
                                                    t0, ns);
    }
}